// Round 13
// baseline (69.120 us; speedup 1.0000x reference)
//
#include <hip/hip_runtime.h>

#define IN_DIM 256
#define OUT_DIM 128
#define SLOPE 0.1f
#define CAP 128   // per-dst bucket capacity; filtered degree ~ Poisson(33), max ~70

typedef short bf16x8 __attribute__((ext_vector_type(8)));
typedef float f32x4  __attribute__((ext_vector_type(4)));
typedef unsigned short ushort4v __attribute__((ext_vector_type(4)));

__device__ __forceinline__ unsigned short f2bf(float f) {
    unsigned u = __builtin_bit_cast(unsigned, f);
    return (unsigned short)((u + 0x7FFFu + ((u >> 16) & 1u)) >> 16);   // RNE
}

// async 16B global->LDS DMA; LDS dest is wave-uniform base + lane*16
__device__ __forceinline__ void gld_lds16(const void* g, void* l) {
    __builtin_amdgcn_global_load_lds(
        (const __attribute__((address_space(1))) void*)g,
        (__attribute__((address_space(3))) void*)l, 16, 0, 0);
}

// ---------------------------------------------------------------------------
// Kernel 0: convert feats (n x 256) and W (128 x 256) fp32 -> bf16 row-major.
// Pure memory-bound (77MB); enables zero-conversion async GEMM staging.
// ---------------------------------------------------------------------------
__global__ __launch_bounds__(256) void cvt_kernel(
    const float* __restrict__ feats, const float* __restrict__ W,
    unsigned short* __restrict__ fb, unsigned short* __restrict__ wb,
    int nf4, int nw4)
{
    const int stride = gridDim.x * blockDim.x;
    const int total = nf4 + nw4;
    for (int i = blockIdx.x * blockDim.x + threadIdx.x; i < total; i += stride) {
        float4 v;
        if (i < nf4) v = reinterpret_cast<const float4*>(feats)[i];
        else         v = reinterpret_cast<const float4*>(W)[i - nf4];
        ushort4v o;
        o[0] = f2bf(v.x); o[1] = f2bf(v.y); o[2] = f2bf(v.z); o[3] = f2bf(v.w);
        if (i < nf4) *reinterpret_cast<ushort4v*>(&fb[4 * (size_t)i]) = o;
        else         *reinterpret_cast<ushort4v*>(&wb[4 * (size_t)(i - nf4)]) = o;
    }
}

// ---------------------------------------------------------------------------
// Kernel 1: emb = feats @ W^T + b via bf16 MFMA, BM=128, 256 threads.
// Staging via async global_load_lds (16B), swizzle applied on the per-lane
// GLOBAL source address (LDS written linearly) -> fragment reads use the
// same XOR as before. Fused: s_dst/s_src scores; needed[]/cur[] init.
// ---------------------------------------------------------------------------
__global__ __launch_bounds__(256) void gemm_mfma_kernel(
    const unsigned short* __restrict__ fb, const unsigned short* __restrict__ wb,
    const float* __restrict__ bias, const float* __restrict__ a,
    unsigned short* __restrict__ emb_bf, float* __restrict__ s_dst,
    float* __restrict__ s_src, int* __restrict__ needed,
    int* __restrict__ cur, int n)
{
    __shared__ __align__(16) unsigned short A_s[128 * 128];
    __shared__ __align__(16) unsigned short W_s[128 * 128];
    __shared__ float sd_l[2][128];
    __shared__ float ss_l[2][128];

    const int t    = threadIdx.x;
    const int lane = t & 63;
    const int wid  = t >> 6;
    const int wr   = wid >> 1;
    const int wc   = wid & 1;
    const int row0 = blockIdx.x * 128;

    if (t < 128) {
        const int ci = row0 + t;
        if (ci < n) { needed[ci] = 0; cur[ci] = 0; }
    }

    const int rlo = lane >> 4;    // 0..3 : row within 4-row issue slot
    const int cA  = lane & 15;    // 16B chunk index within row

    const f32x4 z4 = {0.f, 0.f, 0.f, 0.f};
    f32x4 acc[4][4];
    #pragma unroll
    for (int mi = 0; mi < 4; ++mi)
        #pragma unroll
        for (int ni = 0; ni < 4; ++ni) acc[mi][ni] = z4;

    for (int ph = 0; ph < 2; ++ph) {
        const int k0 = ph * 128;
        if (ph) __syncthreads();

        // ---- async stage A and W: 8 wave-issues each per wave ----
        #pragma unroll
        for (int j = 0; j < 8; ++j) {
            const int slot = wid * 8 + j;          // 0..31, covers 128 rows
            const int r    = slot * 4 + rlo;       // 0..127 (per-lane)
            const int ch   = cA ^ (r & 7);         // pre-swizzled source chunk
            // A rows: fb padded to 128-multiple rows, so row0+r always valid
            gld_lds16(fb + (size_t)(row0 + r) * IN_DIM + k0 + (ch << 3),
                      &A_s[slot * 512]);
            gld_lds16(wb + (size_t)r * IN_DIM + k0 + (ch << 3),
                      &W_s[slot * 512]);
        }
        __syncthreads();   // drains vmcnt -> LDS tiles complete

        // ---- compute: 4 K-steps of 32 ----
        #pragma unroll
        for (int ks = 0; ks < 4; ++ks) {
            const int kf = ks * 32 + (lane >> 4) * 8;
            bf16x8 af[4], wf[4];
            #pragma unroll
            for (int mi = 0; mi < 4; ++mi) {
                const int row = wr * 64 + mi * 16 + (lane & 15);
                const int off = (row * 128 + kf) ^ ((row & 7) << 3);
                af[mi] = *(const bf16x8*)&A_s[off];
            }
            #pragma unroll
            for (int ni = 0; ni < 4; ++ni) {
                const int col = wc * 64 + ni * 16 + (lane & 15);
                const int off = (col * 128 + kf) ^ ((col & 7) << 3);
                wf[ni] = *(const bf16x8*)&W_s[off];
            }
            #pragma unroll
            for (int mi = 0; mi < 4; ++mi)
                #pragma unroll
                for (int ni = 0; ni < 4; ++ni)
                    acc[mi][ni] = __builtin_amdgcn_mfma_f32_16x16x32_bf16(
                        af[mi], wf[ni], acc[mi][ni], 0, 0, 0);
        }
    }

    // ---- epilogue: bias, bf16 emb store, fused score partials ----
    float bcol[4], avd[4], avs[4];
    #pragma unroll
    for (int ni = 0; ni < 4; ++ni) {
        const int col = wc * 64 + ni * 16 + (lane & 15);
        bcol[ni] = bias[col];
        avd[ni]  = a[col];
        avs[ni]  = a[OUT_DIM + col];
    }

    #pragma unroll
    for (int mi = 0; mi < 4; ++mi) {
        #pragma unroll
        for (int j = 0; j < 4; ++j) {
            const int rib = wr * 64 + mi * 16 + (lane >> 4) * 4 + j;
            const int row = row0 + rib;
            float pd = 0.f, ps = 0.f;
            if (row < n) {
                #pragma unroll
                for (int ni = 0; ni < 4; ++ni) {
                    const float v = acc[mi][ni][j] + bcol[ni];
                    emb_bf[(size_t)row * OUT_DIM + wc * 64 + ni * 16 + (lane & 15)] = f2bf(v);
                    pd = fmaf(v, avd[ni], pd);
                    ps = fmaf(v, avs[ni], ps);
                }
            }
            pd += __shfl_xor(pd, 1); ps += __shfl_xor(ps, 1);
            pd += __shfl_xor(pd, 2); ps += __shfl_xor(ps, 2);
            pd += __shfl_xor(pd, 4); ps += __shfl_xor(ps, 4);
            pd += __shfl_xor(pd, 8); ps += __shfl_xor(ps, 8);
            if ((lane & 15) == 0) { sd_l[wc][rib] = pd; ss_l[wc][rib] = ps; }
        }
    }
    __syncthreads();
    if (t < 128) {
        const int row = row0 + t;
        if (row < n) {
            s_dst[row] = sd_l[0][t] + sd_l[1][t];
            s_src[row] = ss_l[0][t] + ss_l[1][t];
        }
    }
}

// ---------------------------------------------------------------------------
// Kernel 2: mark needed destinations (plain store; idempotent)
// ---------------------------------------------------------------------------
__global__ void flag_kernel(const int* __restrict__ node_idx,
                            int* __restrict__ needed, int nb)
{
    const int i = blockIdx.x * blockDim.x + threadIdx.x;
    if (i < nb) needed[node_idx[i]] = 1;
}

// ---------------------------------------------------------------------------
// Kernel 3: needed-filtered scatter (R7 form: 1 edge/thread)
// ---------------------------------------------------------------------------
__global__ __launch_bounds__(256) void scatter_kernel(
    const int* __restrict__ edges, const int* __restrict__ needed,
    int* __restrict__ cur, const float* __restrict__ s_dst,
    const float* __restrict__ s_src, int2* __restrict__ ew, int E)
{
    const int e = blockIdx.x * blockDim.x + threadIdx.x;
    if (e >= E) return;
    const int2 ed = reinterpret_cast<const int2*>(edges)[e];
    if (needed[ed.x]) {
        const float x = s_dst[ed.x] + s_src[ed.y];
        const float w = __expf(x >= 0.f ? x : SLOPE * x);
        const int p = atomicAdd(&cur[ed.x], 1);
        if (p < CAP)
            ew[(size_t)ed.x * CAP + p] = make_int2(ed.y, __float_as_int(w));
    }
}

// ---------------------------------------------------------------------------
// Kernel 4: fused aggregate + output (R7 form: one wave/row, 4-deep unroll)
// ---------------------------------------------------------------------------
__global__ __launch_bounds__(256) void agg_out_kernel(
    const int* __restrict__ node_idx, const int* __restrict__ cur,
    const int2* __restrict__ ew, const unsigned short* __restrict__ emb_bf,
    float* __restrict__ out, int nb)
{
    const int w    = (int)((blockIdx.x * blockDim.x + threadIdx.x) >> 6);
    const int lane = threadIdx.x & 63;
    if (w >= nb) return;

    const int dst = node_idx[w];
    int m = cur[dst];
    if (m > CAP) m = CAP;
    const int2* __restrict__ bucket = ew + (size_t)dst * CAP;

    float accx = 0.f, accy = 0.f, den = 0.f;

    for (int base = 0; base < m; base += 64) {
        const int rem = min(64, m - base);
        int   src = 0;
        float wt  = 0.f;
        if (lane < rem) {
            const int2 q = bucket[base + lane];
            src = q.x;
            wt  = __int_as_float(q.y);
        }
        int i = 0;
        for (; i + 4 <= rem; i += 4) {
            const int   s0 = __shfl(src, i),     s1 = __shfl(src, i + 1);
            const int   s2 = __shfl(src, i + 2), s3 = __shfl(src, i + 3);
            const float w0 = __shfl(wt, i),      w1 = __shfl(wt, i + 1);
            const float w2 = __shfl(wt, i + 2),  w3 = __shfl(wt, i + 3);
            const unsigned b0 = *(const unsigned*)&emb_bf[(size_t)s0 * OUT_DIM + 2 * lane];
            const unsigned b1 = *(const unsigned*)&emb_bf[(size_t)s1 * OUT_DIM + 2 * lane];
            const unsigned b2 = *(const unsigned*)&emb_bf[(size_t)s2 * OUT_DIM + 2 * lane];
            const unsigned b3 = *(const unsigned*)&emb_bf[(size_t)s3 * OUT_DIM + 2 * lane];
            den += (w0 + w1) + (w2 + w3);
            accx = fmaf(w0, __int_as_float((int)(b0 << 16)), accx);
            accy = fmaf(w0, __int_as_float((int)(b0 & 0xFFFF0000u)), accy);
            accx = fmaf(w1, __int_as_float((int)(b1 << 16)), accx);
            accy = fmaf(w1, __int_as_float((int)(b1 & 0xFFFF0000u)), accy);
            accx = fmaf(w2, __int_as_float((int)(b2 << 16)), accx);
            accy = fmaf(w2, __int_as_float((int)(b2 & 0xFFFF0000u)), accy);
            accx = fmaf(w3, __int_as_float((int)(b3 << 16)), accx);
            accy = fmaf(w3, __int_as_float((int)(b3 & 0xFFFF0000u)), accy);
        }
        for (; i < rem; ++i) {
            const int   s0 = __shfl(src, i);
            const float w0 = __shfl(wt, i);
            const unsigned b0 = *(const unsigned*)&emb_bf[(size_t)s0 * OUT_DIM + 2 * lane];
            den += w0;
            accx = fmaf(w0, __int_as_float((int)(b0 << 16)), accx);
            accy = fmaf(w0, __int_as_float((int)(b0 & 0xFFFF0000u)), accy);
        }
    }

    const float inv = 1.0f / den;
    float2 o; o.x = accx * inv; o.y = accy * inv;
    *reinterpret_cast<float2*>(&out[(size_t)w * OUT_DIM + 2 * lane]) = o;
}

// ---------------------------------------------------------------------------
extern "C" void kernel_launch(void* const* d_in, const int* in_sizes, int n_in,
                              void* d_out, int out_size, void* d_ws, size_t ws_size,
                              hipStream_t stream)
{
    const float* feats    = (const float*)d_in[0];
    const float* W        = (const float*)d_in[1];
    const float* bias     = (const float*)d_in[2];
    const float* a        = (const float*)d_in[3];
    const int*   edges    = (const int*)d_in[4];
    const int*   node_idx = (const int*)d_in[5];
    float*       out      = (float*)d_out;

    const int n  = in_sizes[0] / IN_DIM;   // 50000
    const int E  = in_sizes[4] / 2;        // 1650000
    const int nb = in_sizes[5];            // 10000
    const int npad = ((n + 127) / 128) * 128;   // 50048: pad rows for staging

    // Workspace layout (16B-aligned segments):
    char* ws = (char*)d_ws;
    unsigned short* emb_bf = (unsigned short*)ws;
    ws += (size_t)n * OUT_DIM * sizeof(unsigned short);                   // 12.8 MB
    unsigned short* fb = (unsigned short*)ws;
    ws += (size_t)npad * IN_DIM * sizeof(unsigned short);                 // 25.6 MB
    unsigned short* wb = (unsigned short*)ws;
    ws += (size_t)OUT_DIM * IN_DIM * sizeof(unsigned short);              // 64 KB
    float* s_dst = (float*)ws;  ws += (size_t)(n + 4) * sizeof(float);
    float* s_src = (float*)ws;  ws += (size_t)(n + 4) * sizeof(float);
    int*   needed= (int*)ws;    ws += (size_t)(n + 4) * sizeof(int);
    int*   cur   = (int*)ws;    ws += (size_t)(n + 4) * sizeof(int);
    int2*  ew    = (int2*)ws;   ws += (size_t)n * CAP * sizeof(int2);     // 51.2 MB

    const int nf4 = n * IN_DIM / 4;
    const int nw4 = OUT_DIM * IN_DIM / 4;

    cvt_kernel      <<<2048, 256, 0, stream>>>(feats, W, fb, wb, nf4, nw4);
    gemm_mfma_kernel<<<npad / 128, 256, 0, stream>>>(
        fb, wb, bias, a, emb_bf, s_dst, s_src, needed, cur, n);
    flag_kernel     <<<(nb + 255) / 256, 256, 0, stream>>>(node_idx, needed, nb);
    scatter_kernel  <<<(E + 255) / 256, 256, 0, stream>>>(edges, needed, cur, s_dst, s_src, ew, E);
    agg_out_kernel  <<<(nb + 3) / 4, 256, 0, stream>>>(node_idx, cur, ew, emb_bf, out, nb);
}

// Round 14
// 63.336 us; speedup vs baseline: 1.0913x; 1.0913x over previous
//
#include <hip/hip_runtime.h>

#define IN_DIM 256
#define OUT_DIM 128
#define SLOPE 0.1f
#define CAP 128   // per-dst bucket capacity; filtered degree ~ Poisson(33), max ~70

typedef short bf16x8 __attribute__((ext_vector_type(8)));
typedef float f32x4  __attribute__((ext_vector_type(4)));

__device__ __forceinline__ unsigned short f2bf(float f) {
    unsigned u = __builtin_bit_cast(unsigned, f);
    return (unsigned short)((u + 0x7FFFu + ((u >> 16) & 1u)) >> 16);   // RNE
}

// ---------------------------------------------------------------------------
// Kernel 1: emb = feats @ W^T + b via bf16 MFMA, BM=128, 256 threads.
// BURST STAGING (R14): per phase, all 16 A float4 loads issue into registers
// before any LDS store (16KB in flight per wave vs ~32B for the old
// load->convert->store chain); then the same for W. Attacks the measured
// ~1 TB/s staging rate (cvt_kernel proved 6 TB/s is available).
// Fused: s_dst/s_src scores; needed[]/cur[] init; emb stored bf16.
// ---------------------------------------------------------------------------
__global__ __launch_bounds__(256, 2) void gemm_mfma_kernel(
    const float* __restrict__ feats, const float* __restrict__ W,
    const float* __restrict__ bias, const float* __restrict__ a,
    unsigned short* __restrict__ emb_bf, float* __restrict__ s_dst,
    float* __restrict__ s_src, int* __restrict__ needed,
    int* __restrict__ cur, int n)
{
    __shared__ __align__(16) unsigned short A_s[128 * 128];
    __shared__ __align__(16) unsigned short W_s[128 * 128];
    __shared__ float sd_l[2][128];
    __shared__ float ss_l[2][128];

    const int t    = threadIdx.x;
    const int lane = t & 63;
    const int wid  = t >> 6;
    const int wr   = wid >> 1;
    const int wc   = wid & 1;
    const int row0 = blockIdx.x * 128;

    // fused scratch init (kernel-boundary ordering protects readers)
    if (t < 128) {
        const int ci = row0 + t;
        if (ci < n) { needed[ci] = 0; cur[ci] = 0; }
    }

    const f32x4 z4 = {0.f, 0.f, 0.f, 0.f};
    f32x4 acc[4][4];
    #pragma unroll
    for (int mi = 0; mi < 4; ++mi)
        #pragma unroll
        for (int ni = 0; ni < 4; ++ni) acc[mi][ni] = z4;

    for (int ph = 0; ph < 2; ++ph) {
        const int k0 = ph * 128;
        if (ph) __syncthreads();

        // ---- burst A: 16 independent loads, then 8 LDS stores ----
        {
            float4 v0[8], v1[8];
            #pragma unroll
            for (int i = 0; i < 8; ++i) {
                const int g = i * 256 + t;
                const int r = g >> 4;
                const int c = g & 15;
                const int gr = row0 + r;
                v0[i] = make_float4(0.f, 0.f, 0.f, 0.f);
                v1[i] = v0[i];
                if (gr < n) {
                    const float* p = &feats[(size_t)gr * IN_DIM + k0 + c * 8];
                    v0[i] = *(const float4*)p;
                    v1[i] = *(const float4*)(p + 4);
                }
            }
            #pragma unroll
            for (int i = 0; i < 8; ++i) {
                const int g = i * 256 + t;
                const int r = g >> 4;
                const int c = g & 15;
                bf16x8 pk;
                pk[0]=(short)f2bf(v0[i].x); pk[1]=(short)f2bf(v0[i].y);
                pk[2]=(short)f2bf(v0[i].z); pk[3]=(short)f2bf(v0[i].w);
                pk[4]=(short)f2bf(v1[i].x); pk[5]=(short)f2bf(v1[i].y);
                pk[6]=(short)f2bf(v1[i].z); pk[7]=(short)f2bf(v1[i].w);
                const int off = (r * 128 + c * 8) ^ ((r & 7) << 3);
                *(bf16x8*)&A_s[off] = pk;
            }
        }
        // ---- burst W: 16 independent loads, then 8 LDS stores ----
        {
            float4 v0[8], v1[8];
            #pragma unroll
            for (int i = 0; i < 8; ++i) {
                const int g = i * 256 + t;
                const int r = g >> 4;
                const int c = g & 15;
                const float* p = &W[(size_t)r * IN_DIM + k0 + c * 8];
                v0[i] = *(const float4*)p;
                v1[i] = *(const float4*)(p + 4);
            }
            #pragma unroll
            for (int i = 0; i < 8; ++i) {
                const int g = i * 256 + t;
                const int r = g >> 4;
                const int c = g & 15;
                bf16x8 pk;
                pk[0]=(short)f2bf(v0[i].x); pk[1]=(short)f2bf(v0[i].y);
                pk[2]=(short)f2bf(v0[i].z); pk[3]=(short)f2bf(v0[i].w);
                pk[4]=(short)f2bf(v1[i].x); pk[5]=(short)f2bf(v1[i].y);
                pk[6]=(short)f2bf(v1[i].z); pk[7]=(short)f2bf(v1[i].w);
                const int off = (r * 128 + c * 8) ^ ((r & 7) << 3);
                *(bf16x8*)&W_s[off] = pk;
            }
        }
        __syncthreads();

        // ---- compute: 4 K-steps of 32 ----
        #pragma unroll
        for (int ks = 0; ks < 4; ++ks) {
            const int kf = ks * 32 + (lane >> 4) * 8;
            bf16x8 af[4], wf[4];
            #pragma unroll
            for (int mi = 0; mi < 4; ++mi) {
                const int row = wr * 64 + mi * 16 + (lane & 15);
                const int off = (row * 128 + kf) ^ ((row & 7) << 3);
                af[mi] = *(const bf16x8*)&A_s[off];
            }
            #pragma unroll
            for (int ni = 0; ni < 4; ++ni) {
                const int col = wc * 64 + ni * 16 + (lane & 15);
                const int off = (col * 128 + kf) ^ ((col & 7) << 3);
                wf[ni] = *(const bf16x8*)&W_s[off];
            }
            #pragma unroll
            for (int mi = 0; mi < 4; ++mi)
                #pragma unroll
                for (int ni = 0; ni < 4; ++ni)
                    acc[mi][ni] = __builtin_amdgcn_mfma_f32_16x16x32_bf16(
                        af[mi], wf[ni], acc[mi][ni], 0, 0, 0);
        }
    }

    // ---- epilogue: bias, bf16 emb store, fused score partials ----
    float bcol[4], avd[4], avs[4];
    #pragma unroll
    for (int ni = 0; ni < 4; ++ni) {
        const int col = wc * 64 + ni * 16 + (lane & 15);
        bcol[ni] = bias[col];
        avd[ni]  = a[col];
        avs[ni]  = a[OUT_DIM + col];
    }

    #pragma unroll
    for (int mi = 0; mi < 4; ++mi) {
        #pragma unroll
        for (int j = 0; j < 4; ++j) {
            const int rib = wr * 64 + mi * 16 + (lane >> 4) * 4 + j;
            const int row = row0 + rib;
            float pd = 0.f, ps = 0.f;
            if (row < n) {
                #pragma unroll
                for (int ni = 0; ni < 4; ++ni) {
                    const float v = acc[mi][ni][j] + bcol[ni];
                    emb_bf[(size_t)row * OUT_DIM + wc * 64 + ni * 16 + (lane & 15)] = f2bf(v);
                    pd = fmaf(v, avd[ni], pd);
                    ps = fmaf(v, avs[ni], ps);
                }
            }
            pd += __shfl_xor(pd, 1); ps += __shfl_xor(ps, 1);
            pd += __shfl_xor(pd, 2); ps += __shfl_xor(ps, 2);
            pd += __shfl_xor(pd, 4); ps += __shfl_xor(ps, 4);
            pd += __shfl_xor(pd, 8); ps += __shfl_xor(ps, 8);
            if ((lane & 15) == 0) { sd_l[wc][rib] = pd; ss_l[wc][rib] = ps; }
        }
    }
    __syncthreads();
    if (t < 128) {
        const int row = row0 + t;
        if (row < n) {
            s_dst[row] = sd_l[0][t] + sd_l[1][t];
            s_src[row] = ss_l[0][t] + ss_l[1][t];
        }
    }
}

// ---------------------------------------------------------------------------
// Kernel 2: mark needed destinations (plain store; idempotent)
// ---------------------------------------------------------------------------
__global__ void flag_kernel(const int* __restrict__ node_idx,
                            int* __restrict__ needed, int nb)
{
    const int i = blockIdx.x * blockDim.x + threadIdx.x;
    if (i < nb) needed[node_idx[i]] = 1;
}

// ---------------------------------------------------------------------------
// Kernel 3: needed-filtered scatter into per-dst buckets (R7-proven form).
// ---------------------------------------------------------------------------
__global__ __launch_bounds__(256) void scatter_kernel(
    const int* __restrict__ edges, const int* __restrict__ needed,
    int* __restrict__ cur, const float* __restrict__ s_dst,
    const float* __restrict__ s_src, int2* __restrict__ ew, int E)
{
    const int e = blockIdx.x * blockDim.x + threadIdx.x;
    if (e >= E) return;
    const int2 ed = reinterpret_cast<const int2*>(edges)[e];
    if (needed[ed.x]) {
        const float x = s_dst[ed.x] + s_src[ed.y];
        const float w = __expf(x >= 0.f ? x : SLOPE * x);
        const int p = atomicAdd(&cur[ed.x], 1);
        if (p < CAP)
            ew[(size_t)ed.x * CAP + p] = make_int2(ed.y, __float_as_int(w));
    }
}

// ---------------------------------------------------------------------------
// Kernel 4: fused aggregate + output (R7-proven form).
// ---------------------------------------------------------------------------
__global__ __launch_bounds__(256) void agg_out_kernel(
    const int* __restrict__ node_idx, const int* __restrict__ cur,
    const int2* __restrict__ ew, const unsigned short* __restrict__ emb_bf,
    float* __restrict__ out, int nb)
{
    const int w    = (int)((blockIdx.x * blockDim.x + threadIdx.x) >> 6);
    const int lane = threadIdx.x & 63;
    if (w >= nb) return;

    const int dst = node_idx[w];
    int m = cur[dst];
    if (m > CAP) m = CAP;
    const int2* __restrict__ bucket = ew + (size_t)dst * CAP;

    float accx = 0.f, accy = 0.f, den = 0.f;

    for (int base = 0; base < m; base += 64) {
        const int rem = min(64, m - base);
        int   src = 0;
        float wt  = 0.f;
        if (lane < rem) {
            const int2 q = bucket[base + lane];
            src = q.x;
            wt  = __int_as_float(q.y);
        }
        int i = 0;
        for (; i + 4 <= rem; i += 4) {
            const int   s0 = __shfl(src, i),     s1 = __shfl(src, i + 1);
            const int   s2 = __shfl(src, i + 2), s3 = __shfl(src, i + 3);
            const float w0 = __shfl(wt, i),      w1 = __shfl(wt, i + 1);
            const float w2 = __shfl(wt, i + 2),  w3 = __shfl(wt, i + 3);
            const unsigned b0 = *(const unsigned*)&emb_bf[(size_t)s0 * OUT_DIM + 2 * lane];
            const unsigned b1 = *(const unsigned*)&emb_bf[(size_t)s1 * OUT_DIM + 2 * lane];
            const unsigned b2 = *(const unsigned*)&emb_bf[(size_t)s2 * OUT_DIM + 2 * lane];
            const unsigned b3 = *(const unsigned*)&emb_bf[(size_t)s3 * OUT_DIM + 2 * lane];
            den += (w0 + w1) + (w2 + w3);
            accx = fmaf(w0, __int_as_float((int)(b0 << 16)), accx);
            accy = fmaf(w0, __int_as_float((int)(b0 & 0xFFFF0000u)), accy);
            accx = fmaf(w1, __int_as_float((int)(b1 << 16)), accx);
            accy = fmaf(w1, __int_as_float((int)(b1 & 0xFFFF0000u)), accy);
            accx = fmaf(w2, __int_as_float((int)(b2 << 16)), accx);
            accy = fmaf(w2, __int_as_float((int)(b2 & 0xFFFF0000u)), accy);
            accx = fmaf(w3, __int_as_float((int)(b3 << 16)), accx);
            accy = fmaf(w3, __int_as_float((int)(b3 & 0xFFFF0000u)), accy);
        }
        for (; i < rem; ++i) {
            const int   s0 = __shfl(src, i);
            const float w0 = __shfl(wt, i);
            const unsigned b0 = *(const unsigned*)&emb_bf[(size_t)s0 * OUT_DIM + 2 * lane];
            den += w0;
            accx = fmaf(w0, __int_as_float((int)(b0 << 16)), accx);
            accy = fmaf(w0, __int_as_float((int)(b0 & 0xFFFF0000u)), accy);
        }
    }

    const float inv = 1.0f / den;
    float2 o; o.x = accx * inv; o.y = accy * inv;
    *reinterpret_cast<float2*>(&out[(size_t)w * OUT_DIM + 2 * lane]) = o;
}

// ---------------------------------------------------------------------------
extern "C" void kernel_launch(void* const* d_in, const int* in_sizes, int n_in,
                              void* d_out, int out_size, void* d_ws, size_t ws_size,
                              hipStream_t stream)
{
    const float* feats    = (const float*)d_in[0];
    const float* W        = (const float*)d_in[1];
    const float* bias     = (const float*)d_in[2];
    const float* a        = (const float*)d_in[3];
    const int*   edges    = (const int*)d_in[4];
    const int*   node_idx = (const int*)d_in[5];
    float*       out      = (float*)d_out;

    const int n  = in_sizes[0] / IN_DIM;   // 50000
    const int E  = in_sizes[4] / 2;        // 1650000
    const int nb = in_sizes[5];            // 10000

    // Workspace layout (16B-aligned segments):
    char* ws = (char*)d_ws;
    unsigned short* emb_bf = (unsigned short*)ws;
    ws += (size_t)n * OUT_DIM * sizeof(unsigned short);                 // 12.8 MB
    float* s_dst = (float*)ws;  ws += (size_t)(n + 4) * sizeof(float);
    float* s_src = (float*)ws;  ws += (size_t)(n + 4) * sizeof(float);
    int*   needed= (int*)ws;    ws += (size_t)(n + 4) * sizeof(int);
    int*   cur   = (int*)ws;    ws += (size_t)(n + 4) * sizeof(int);
    int2*  ew    = (int2*)ws;   ws += (size_t)n * CAP * sizeof(int2);   // 51.2 MB

    gemm_mfma_kernel<<<(n + 127) / 128, 256, 0, stream>>>(
        feats, W, bias, a, emb_bf, s_dst, s_src, needed, cur, n);
    flag_kernel     <<<(nb + 255) / 256, 256, 0, stream>>>(node_idx, needed, nb);
    scatter_kernel  <<<(E + 255) / 256, 256, 0, stream>>>(edges, needed, cur, s_dst, s_src, ew, E);
    agg_out_kernel  <<<(nb + 3) / 4, 256, 0, stream>>>(node_idx, cur, ew, emb_bf, out, nb);
}

// Round 15
// 63.299 us; speedup vs baseline: 1.0920x; 1.0006x over previous
//
#include <hip/hip_runtime.h>

#define IN_DIM 256
#define OUT_DIM 128
#define SLOPE 0.1f
#define CAP 128   // per-dst bucket capacity; filtered degree ~ Poisson(33), max ~70

typedef short bf16x8 __attribute__((ext_vector_type(8)));
typedef float f32x4  __attribute__((ext_vector_type(4)));

__device__ __forceinline__ unsigned short f2bf(float f) {
    unsigned u = __builtin_bit_cast(unsigned, f);
    return (unsigned short)((u + 0x7FFFu + ((u >> 16) & 1u)) >> 16);   // RNE
}

__device__ __forceinline__ void pack8(const float4& v0, const float4& v1, bf16x8& pk) {
    pk[0]=(short)f2bf(v0.x); pk[1]=(short)f2bf(v0.y);
    pk[2]=(short)f2bf(v0.z); pk[3]=(short)f2bf(v0.w);
    pk[4]=(short)f2bf(v1.x); pk[5]=(short)f2bf(v1.y);
    pk[6]=(short)f2bf(v1.z); pk[7]=(short)f2bf(v1.w);
}

// ---------------------------------------------------------------------------
// Kernel 1: emb = feats @ W^T + b via bf16 MFMA, BM=128, 256 threads.
// R15: staging = depth-4 rolling pipeline (4 chunks = 32 VGPR in flight,
// consume-then-refill, compile-time indices) + uniform bounds branch
// (only the tail block takes the guarded path). Attacks the measured
// latency-serialization: 64 serial loads x ~900cyc matched the 38us gemm.
// Fused: s_dst/s_src scores; needed[]/cur[] init; emb stored bf16.
// ---------------------------------------------------------------------------
__global__ __launch_bounds__(256, 2) void gemm_mfma_kernel(
    const float* __restrict__ feats, const float* __restrict__ W,
    const float* __restrict__ bias, const float* __restrict__ a,
    unsigned short* __restrict__ emb_bf, float* __restrict__ s_dst,
    float* __restrict__ s_src, int* __restrict__ needed,
    int* __restrict__ cur, int n)
{
    __shared__ __align__(16) unsigned short A_s[128 * 128];
    __shared__ __align__(16) unsigned short W_s[128 * 128];
    __shared__ float sd_l[2][128];
    __shared__ float ss_l[2][128];

    const int t    = threadIdx.x;
    const int lane = t & 63;
    const int wid  = t >> 6;
    const int wr   = wid >> 1;
    const int wc   = wid & 1;
    const int row0 = blockIdx.x * 128;

    // fused scratch init (kernel-boundary ordering protects readers)
    if (t < 128) {
        const int ci = row0 + t;
        if (ci < n) { needed[ci] = 0; cur[ci] = 0; }
    }

    const int tr = t >> 4;    // 0..15 : row within 16-row chunk stripe
    const int tc = t & 15;    // 16B-pair chunk column

    const bool full = (row0 + 128 <= n);   // uniform across block

    const f32x4 z4 = {0.f, 0.f, 0.f, 0.f};
    f32x4 acc[4][4];
    #pragma unroll
    for (int mi = 0; mi < 4; ++mi)
        #pragma unroll
        for (int ni = 0; ni < 4; ++ni) acc[mi][ni] = z4;

    for (int ph = 0; ph < 2; ++ph) {
        const int k0 = ph * 128;
        if (ph) __syncthreads();

        if (full) {
            // ---- A: depth-4 rolling pipeline over 8 chunks ----
            {
                const float* pa = &feats[(size_t)(row0 + tr) * IN_DIM + k0 + tc * 8];
                float4 b0[4], b1[4];
                #pragma unroll
                for (int i = 0; i < 4; ++i) {
                    b0[i] = *(const float4*)(pa + (size_t)i * 16 * IN_DIM);
                    b1[i] = *(const float4*)(pa + (size_t)i * 16 * IN_DIM + 4);
                }
                #pragma unroll
                for (int i = 0; i < 8; ++i) {
                    const int r = i * 16 + tr;
                    bf16x8 pk; pack8(b0[i & 3], b1[i & 3], pk);
                    const int off = (r * 128 + tc * 8) ^ ((r & 7) << 3);
                    *(bf16x8*)&A_s[off] = pk;
                    if (i + 4 < 8) {
                        b0[i & 3] = *(const float4*)(pa + (size_t)(i + 4) * 16 * IN_DIM);
                        b1[i & 3] = *(const float4*)(pa + (size_t)(i + 4) * 16 * IN_DIM + 4);
                    }
                }
            }
            // ---- W: depth-4 rolling pipeline over 8 chunks ----
            {
                const float* pw = &W[(size_t)tr * IN_DIM + k0 + tc * 8];
                float4 b0[4], b1[4];
                #pragma unroll
                for (int i = 0; i < 4; ++i) {
                    b0[i] = *(const float4*)(pw + (size_t)i * 16 * IN_DIM);
                    b1[i] = *(const float4*)(pw + (size_t)i * 16 * IN_DIM + 4);
                }
                #pragma unroll
                for (int i = 0; i < 8; ++i) {
                    const int r = i * 16 + tr;
                    bf16x8 pk; pack8(b0[i & 3], b1[i & 3], pk);
                    const int off = (r * 128 + tc * 8) ^ ((r & 7) << 3);
                    *(bf16x8*)&W_s[off] = pk;
                    if (i + 4 < 8) {
                        b0[i & 3] = *(const float4*)(pw + (size_t)(i + 4) * 16 * IN_DIM);
                        b1[i & 3] = *(const float4*)(pw + (size_t)(i + 4) * 16 * IN_DIM + 4);
                    }
                }
            }
        } else {
            // tail block: guarded serial staging (one block only)
            #pragma unroll
            for (int i = 0; i < 8; ++i) {
                const int r = i * 16 + tr;
                const int gr = row0 + r;
                float4 v0 = make_float4(0.f, 0.f, 0.f, 0.f), v1 = v0;
                if (gr < n) {
                    const float* p = &feats[(size_t)gr * IN_DIM + k0 + tc * 8];
                    v0 = *(const float4*)p;
                    v1 = *(const float4*)(p + 4);
                }
                bf16x8 pk; pack8(v0, v1, pk);
                const int off = (r * 128 + tc * 8) ^ ((r & 7) << 3);
                *(bf16x8*)&A_s[off] = pk;
            }
            #pragma unroll
            for (int i = 0; i < 8; ++i) {
                const int r = i * 16 + tr;
                const float* p = &W[(size_t)r * IN_DIM + k0 + tc * 8];
                const float4 v0 = *(const float4*)p;
                const float4 v1 = *(const float4*)(p + 4);
                bf16x8 pk; pack8(v0, v1, pk);
                const int off = (r * 128 + tc * 8) ^ ((r & 7) << 3);
                *(bf16x8*)&W_s[off] = pk;
            }
        }
        __syncthreads();

        // ---- compute: 4 K-steps of 32 ----
        #pragma unroll
        for (int ks = 0; ks < 4; ++ks) {
            const int kf = ks * 32 + (lane >> 4) * 8;
            bf16x8 af[4], wf[4];
            #pragma unroll
            for (int mi = 0; mi < 4; ++mi) {
                const int row = wr * 64 + mi * 16 + (lane & 15);
                const int off = (row * 128 + kf) ^ ((row & 7) << 3);
                af[mi] = *(const bf16x8*)&A_s[off];
            }
            #pragma unroll
            for (int ni = 0; ni < 4; ++ni) {
                const int col = wc * 64 + ni * 16 + (lane & 15);
                const int off = (col * 128 + kf) ^ ((col & 7) << 3);
                wf[ni] = *(const bf16x8*)&W_s[off];
            }
            #pragma unroll
            for (int mi = 0; mi < 4; ++mi)
                #pragma unroll
                for (int ni = 0; ni < 4; ++ni)
                    acc[mi][ni] = __builtin_amdgcn_mfma_f32_16x16x32_bf16(
                        af[mi], wf[ni], acc[mi][ni], 0, 0, 0);
        }
    }

    // ---- epilogue: bias, bf16 emb store, fused score partials ----
    float bcol[4], avd[4], avs[4];
    #pragma unroll
    for (int ni = 0; ni < 4; ++ni) {
        const int col = wc * 64 + ni * 16 + (lane & 15);
        bcol[ni] = bias[col];
        avd[ni]  = a[col];
        avs[ni]  = a[OUT_DIM + col];
    }

    #pragma unroll
    for (int mi = 0; mi < 4; ++mi) {
        #pragma unroll
        for (int j = 0; j < 4; ++j) {
            const int rib = wr * 64 + mi * 16 + (lane >> 4) * 4 + j;
            const int row = row0 + rib;
            float pd = 0.f, ps = 0.f;
            if (row < n) {
                #pragma unroll
                for (int ni = 0; ni < 4; ++ni) {
                    const float v = acc[mi][ni][j] + bcol[ni];
                    emb_bf[(size_t)row * OUT_DIM + wc * 64 + ni * 16 + (lane & 15)] = f2bf(v);
                    pd = fmaf(v, avd[ni], pd);
                    ps = fmaf(v, avs[ni], ps);
                }
            }
            pd += __shfl_xor(pd, 1); ps += __shfl_xor(ps, 1);
            pd += __shfl_xor(pd, 2); ps += __shfl_xor(ps, 2);
            pd += __shfl_xor(pd, 4); ps += __shfl_xor(ps, 4);
            pd += __shfl_xor(pd, 8); ps += __shfl_xor(ps, 8);
            if ((lane & 15) == 0) { sd_l[wc][rib] = pd; ss_l[wc][rib] = ps; }
        }
    }
    __syncthreads();
    if (t < 128) {
        const int row = row0 + t;
        if (row < n) {
            s_dst[row] = sd_l[0][t] + sd_l[1][t];
            s_src[row] = ss_l[0][t] + ss_l[1][t];
        }
    }
}

// ---------------------------------------------------------------------------
// Kernel 2: mark needed destinations (plain store; idempotent)
// ---------------------------------------------------------------------------
__global__ void flag_kernel(const int* __restrict__ node_idx,
                            int* __restrict__ needed, int nb)
{
    const int i = blockIdx.x * blockDim.x + threadIdx.x;
    if (i < nb) needed[node_idx[i]] = 1;
}

// ---------------------------------------------------------------------------
// Kernel 3: needed-filtered scatter into per-dst buckets (R7-proven form).
// ---------------------------------------------------------------------------
__global__ __launch_bounds__(256) void scatter_kernel(
    const int* __restrict__ edges, const int* __restrict__ needed,
    int* __restrict__ cur, const float* __restrict__ s_dst,
    const float* __restrict__ s_src, int2* __restrict__ ew, int E)
{
    const int e = blockIdx.x * blockDim.x + threadIdx.x;
    if (e >= E) return;
    const int2 ed = reinterpret_cast<const int2*>(edges)[e];
    if (needed[ed.x]) {
        const float x = s_dst[ed.x] + s_src[ed.y];
        const float w = __expf(x >= 0.f ? x : SLOPE * x);
        const int p = atomicAdd(&cur[ed.x], 1);
        if (p < CAP)
            ew[(size_t)ed.x * CAP + p] = make_int2(ed.y, __float_as_int(w));
    }
}

// ---------------------------------------------------------------------------
// Kernel 4: fused aggregate + output (R7-proven form).
// ---------------------------------------------------------------------------
__global__ __launch_bounds__(256) void agg_out_kernel(
    const int* __restrict__ node_idx, const int* __restrict__ cur,
    const int2* __restrict__ ew, const unsigned short* __restrict__ emb_bf,
    float* __restrict__ out, int nb)
{
    const int w    = (int)((blockIdx.x * blockDim.x + threadIdx.x) >> 6);
    const int lane = threadIdx.x & 63;
    if (w >= nb) return;

    const int dst = node_idx[w];
    int m = cur[dst];
    if (m > CAP) m = CAP;
    const int2* __restrict__ bucket = ew + (size_t)dst * CAP;

    float accx = 0.f, accy = 0.f, den = 0.f;

    for (int base = 0; base < m; base += 64) {
        const int rem = min(64, m - base);
        int   src = 0;
        float wt  = 0.f;
        if (lane < rem) {
            const int2 q = bucket[base + lane];
            src = q.x;
            wt  = __int_as_float(q.y);
        }
        int i = 0;
        for (; i + 4 <= rem; i += 4) {
            const int   s0 = __shfl(src, i),     s1 = __shfl(src, i + 1);
            const int   s2 = __shfl(src, i + 2), s3 = __shfl(src, i + 3);
            const float w0 = __shfl(wt, i),      w1 = __shfl(wt, i + 1);
            const float w2 = __shfl(wt, i + 2),  w3 = __shfl(wt, i + 3);
            const unsigned b0 = *(const unsigned*)&emb_bf[(size_t)s0 * OUT_DIM + 2 * lane];
            const unsigned b1 = *(const unsigned*)&emb_bf[(size_t)s1 * OUT_DIM + 2 * lane];
            const unsigned b2 = *(const unsigned*)&emb_bf[(size_t)s2 * OUT_DIM + 2 * lane];
            const unsigned b3 = *(const unsigned*)&emb_bf[(size_t)s3 * OUT_DIM + 2 * lane];
            den += (w0 + w1) + (w2 + w3);
            accx = fmaf(w0, __int_as_float((int)(b0 << 16)), accx);
            accy = fmaf(w0, __int_as_float((int)(b0 & 0xFFFF0000u)), accy);
            accx = fmaf(w1, __int_as_float((int)(b1 << 16)), accx);
            accy = fmaf(w1, __int_as_float((int)(b1 & 0xFFFF0000u)), accy);
            accx = fmaf(w2, __int_as_float((int)(b2 << 16)), accx);
            accy = fmaf(w2, __int_as_float((int)(b2 & 0xFFFF0000u)), accy);
            accx = fmaf(w3, __int_as_float((int)(b3 << 16)), accx);
            accy = fmaf(w3, __int_as_float((int)(b3 & 0xFFFF0000u)), accy);
        }
        for (; i < rem; ++i) {
            const int   s0 = __shfl(src, i);
            const float w0 = __shfl(wt, i);
            const unsigned b0 = *(const unsigned*)&emb_bf[(size_t)s0 * OUT_DIM + 2 * lane];
            den += w0;
            accx = fmaf(w0, __int_as_float((int)(b0 << 16)), accx);
            accy = fmaf(w0, __int_as_float((int)(b0 & 0xFFFF0000u)), accy);
        }
    }

    const float inv = 1.0f / den;
    float2 o; o.x = accx * inv; o.y = accy * inv;
    *reinterpret_cast<float2*>(&out[(size_t)w * OUT_DIM + 2 * lane]) = o;
}

// ---------------------------------------------------------------------------
extern "C" void kernel_launch(void* const* d_in, const int* in_sizes, int n_in,
                              void* d_out, int out_size, void* d_ws, size_t ws_size,
                              hipStream_t stream)
{
    const float* feats    = (const float*)d_in[0];
    const float* W        = (const float*)d_in[1];
    const float* bias     = (const float*)d_in[2];
    const float* a        = (const float*)d_in[3];
    const int*   edges    = (const int*)d_in[4];
    const int*   node_idx = (const int*)d_in[5];
    float*       out      = (float*)d_out;

    const int n  = in_sizes[0] / IN_DIM;   // 50000
    const int E  = in_sizes[4] / 2;        // 1650000
    const int nb = in_sizes[5];            // 10000

    // Workspace layout (16B-aligned segments):
    char* ws = (char*)d_ws;
    unsigned short* emb_bf = (unsigned short*)ws;
    ws += (size_t)n * OUT_DIM * sizeof(unsigned short);                 // 12.8 MB
    float* s_dst = (float*)ws;  ws += (size_t)(n + 4) * sizeof(float);
    float* s_src = (float*)ws;  ws += (size_t)(n + 4) * sizeof(float);
    int*   needed= (int*)ws;    ws += (size_t)(n + 4) * sizeof(int);
    int*   cur   = (int*)ws;    ws += (size_t)(n + 4) * sizeof(int);
    int2*  ew    = (int2*)ws;   ws += (size_t)n * CAP * sizeof(int2);   // 51.2 MB

    gemm_mfma_kernel<<<(n + 127) / 128, 256, 0, stream>>>(
        feats, W, bias, a, emb_bf, s_dst, s_src, needed, cur, n);
    flag_kernel     <<<(nb + 255) / 256, 256, 0, stream>>>(node_idx, needed, nb);
    scatter_kernel  <<<(E + 255) / 256, 256, 0, stream>>>(edges, needed, cur, s_dst, s_src, ew, E);
    agg_out_kernel  <<<(nb + 3) / 4, 256, 0, stream>>>(node_idx, cur, ew, emb_bf, out, nb);
}